// Round 20
// baseline (331.812 us; speedup 1.0000x reference)
//
#include <hip/hip_runtime.h>

typedef unsigned int uint;
typedef short bf16x8 __attribute__((ext_vector_type(8)));
typedef float f32x4 __attribute__((ext_vector_type(4)));

#define N_NODES 100000
#define E_EDGES 1600000
#define L_LAYERS 3
#define G_GRAPHS 128
#define OUT_F 10
#define BN_EPS 1e-5f

#define BSHIFT 7                          // 128-node stripes
#define NSTRIPE ((N_NODES + 127) >> 7)    // 782
#define CHUNK 2048
#define NCHUNK ((E_EDGES + CHUNK - 1) / CHUNK)   // 782
#define PAD8(d) (((d) + 7) & ~7)
#define BCAP (2048 * 103)                 // per-XCD queue capacity (pairs)
#define FB_GRID (103 * 8)
#define SCAP 2560                         // per-stripe queue capacity (pairs)
#define SNBR 3584                         // per-stripe nbr region (ints)

// bf16 pack (RTNE) / unpack helpers
__device__ __forceinline__ uint bf_pack(float a, float b) {
    uint ua = __float_as_uint(a);
    ua = (ua + 0x7fffu + ((ua >> 16) & 1u)) >> 16;
    uint ub = __float_as_uint(b);
    ub = (ub + 0x7fffu + ((ub >> 16) & 1u)) >> 16;
    return ua | (ub << 16);
}
__device__ __forceinline__ unsigned short bf1(float a) {
    uint ua = __float_as_uint(a);
    return (unsigned short)((ua + 0x7fffu + ((ua >> 16) & 1u)) >> 16);
}
__device__ __forceinline__ float lo16(uint u) { return __uint_as_float(u << 16); }
__device__ __forceinline__ float hi16(uint u) { return __uint_as_float(u & 0xffff0000u); }

// -------------------- init queue cursors + sentinel index block -----------
__global__ __launch_bounds__(256) void init_kernel(int* __restrict__ gcur,
                                                   int* __restrict__ scur,
                                                   int* __restrict__ sent) {
    int t = blockIdx.x * 256 + threadIdx.x;
    if (t < 8) gcur[t] = t * BCAP;
    if (t < 16) sent[t] = N_NODES;
    if (t < NSTRIPE) scur[t] = t * SCAP;
}

// ---- fill pass A: bin edges into 8 per-XCD queues (single read of ei) ----
__global__ __launch_bounds__(256) void fillA_kernel(
    const int* __restrict__ src, const int* __restrict__ dst,
    int* __restrict__ gcur, int2* __restrict__ epair) {
    __shared__ int lcnt[8];
    __shared__ int lbase[8];
    int tid = threadIdx.x;
    int base = blockIdx.x * CHUNK;
    if (tid < 8) lcnt[tid] = 0;
    __syncthreads();

    int sd[8], ss[8], bk[8], off[8];
    #pragma unroll
    for (int it = 0; it < 8; ++it) {
        int e = base + it * 256 + tid;
        bk[it] = -1;
        if (e < E_EDGES) {
            sd[it] = dst[e];
            ss[it] = src[e];
            bk[it] = (sd[it] >> BSHIFT) & 7;
            off[it] = atomicAdd(&lcnt[bk[it]], 1);
        }
    }
    __syncthreads();
    if (tid < 8) lbase[tid] = atomicAdd(&gcur[tid], lcnt[tid]);
    __syncthreads();
    #pragma unroll
    for (int it = 0; it < 8; ++it) {
        if (bk[it] >= 0)
            epair[lbase[bk[it]] + off[it]] = make_int2(ss[it], sd[it]);
    }
}

// ---- fill pass B2: bin XCD queue by stripe (98 buckets per XCD) ----------
__global__ __launch_bounds__(256) void fillB2_kernel(
    const int2* __restrict__ epair1, const int* __restrict__ gcur,
    int* __restrict__ scur, int2* __restrict__ epair2) {
    __shared__ int lcnt[98];
    __shared__ int lbase[98];
    int tid = threadIdx.x;
    int g = blockIdx.x & 7;
    int c = blockIdx.x >> 3;
    int ebeg = g * BCAP + c * CHUNK;
    int eend = gcur[g];
    if (tid < 98) lcnt[tid] = 0;
    __syncthreads();

    int2 pp[8]; int bk[8], off[8];
    #pragma unroll
    for (int it = 0; it < 8; ++it) {
        int i = ebeg + it * 256 + tid;
        bk[it] = -1;
        if (i < eend) {
            pp[it] = epair1[i];
            bk[it] = pp[it].y >> 10;               // fine bucket within XCD
            off[it] = atomicAdd(&lcnt[bk[it]], 1);
        }
    }
    __syncthreads();
    if (tid < 98 && lcnt[tid] > 0)
        lbase[tid] = atomicAdd(&scur[(tid << 3) | g], lcnt[tid]);
    __syncthreads();
    #pragma unroll
    for (int it = 0; it < 8; ++it) {
        if (bk[it] >= 0)
            epair2[lbase[bk[it]] + off[it]] = pp[it];
    }
}

// ---- fill pass C2: per-stripe degree-count + scan + place + seq write ----
__global__ __launch_bounds__(256) void fillC2_kernel(
    const int2* __restrict__ epair2, const int* __restrict__ scur,
    int* __restrict__ rbeg, int* __restrict__ rend, int* __restrict__ nbr) {
    __shared__ int cnt[128];
    __shared__ int loc[128];
    __shared__ int off[128];
    __shared__ int buf[SNBR];
    __shared__ int stotal;
    int s = blockIdx.x;
    int tid = threadIdx.x;
    int node0 = s << 7;
    int qbeg = s * SCAP;
    int qend = scur[s];                    // base + count after fillB2
    if (tid < 128) cnt[tid] = 0;
    __syncthreads();

    for (int i = qbeg + tid; i < qend; i += 256)
        atomicAdd(&cnt[epair2[i].y & 127], 1);
    __syncthreads();

    int v = (tid < 128) ? PAD8(cnt[tid]) : 0;
    if (tid < 128) loc[tid] = v;
    __syncthreads();
    for (int o = 1; o < 128; o <<= 1) {
        int u = (tid < 128 && tid >= o) ? loc[tid - o] : 0;
        __syncthreads();
        if (tid < 128) loc[tid] += u;
        __syncthreads();
    }
    int sbase = s * SNBR;
    if (tid < 128) {
        int ex = loc[tid] - v;             // exclusive prefix
        off[tid] = ex;
        int node = node0 + tid;
        if (node < N_NODES) {
            rbeg[node] = sbase + ex;
            rend[node] = sbase + ex + v;   // padded end
        }
    }
    if (tid == 0) stotal = loc[127];
    __syncthreads();
    int total = stotal;

    for (int i = tid; i < total; i += 256) buf[i] = N_NODES;   // sentinels
    __syncthreads();

    for (int i = qbeg + tid; i < qend; i += 256) {
        int2 p = epair2[i];
        int pos = atomicAdd(&off[p.y & 127], 1);
        buf[pos] = p.x;
    }
    __syncthreads();

    for (int i = tid * 4; i < total; i += 1024)
        *reinterpret_cast<int4*>(nbr + sbase + i) = *reinterpret_cast<const int4*>(buf + i);
}

// -------------------- x f32 -> bf16 (layer 0 only) ------------------------
__global__ __launch_bounds__(256) void tobf_kernel(const float* __restrict__ x,
                                                   uint* __restrict__ xbf) {
    int i = blockIdx.x * 256 + threadIdx.x;   // N*8 threads, 8 floats each
    if (i < N_NODES * 8) {
        float4 a = reinterpret_cast<const float4*>(x)[i * 2];
        float4 b = reinterpret_cast<const float4*>(x)[i * 2 + 1];
        uint4 o;
        o.x = bf_pack(a.x, a.y);
        o.y = bf_pack(a.z, a.w);
        o.z = bf_pack(b.x, b.y);
        o.w = bf_pack(b.z, b.w);
        reinterpret_cast<uint4*>(xbf)[i] = o;
    }
    if (i < 8) reinterpret_cast<uint4*>(xbf)[N_NODES * 8 + i] = make_uint4(0, 0, 0, 0);
}

#define ACC8(vv, t0, t1, t2, t3, t4, t5, t6, t7) \
    t0 += lo16(vv.x); t1 += hi16(vv.x); t2 += lo16(vv.y); t3 += hi16(vv.y); \
    t4 += lo16(vv.z); t5 += hi16(vv.z); t6 += lo16(vv.w); t7 += hi16(vv.w);

// ------- fused gather (2-row interleaved MLP) + MFMA GEMM1 + BN stats -----
__global__ __launch_bounds__(256) void gemm1_fused_kernel(
    const uint* __restrict__ xbf, const int* __restrict__ rbeg,
    const int* __restrict__ rend, const int* __restrict__ nbr,
    const int* __restrict__ sent,
    const float* __restrict__ W1, const float* __restrict__ b1,
    unsigned short* __restrict__ h16, float* __restrict__ stats) {
    __shared__ unsigned short sA[64][72];        // bf16 agg tile (pad: 2-way alias)
    __shared__ unsigned short sW[64][72];        // bf16 W^T [col][k]
    int tid = threadIdx.x;
    int row0 = blockIdx.x * 64;

    // stage W1 transposed to [col][k]
    for (int i = tid; i < 1024; i += 256) {
        int k = i >> 4, cb = (i & 15) * 4;
        float4 w = reinterpret_cast<const float4*>(W1)[i];
        sW[cb + 0][k] = bf1(w.x);
        sW[cb + 1][k] = bf1(w.y);
        sW[cb + 2][k] = bf1(w.z);
        sW[cb + 3][k] = bf1(w.w);
    }

    const uint4* xb4 = reinterpret_cast<const uint4*>(xbf);
    int c8 = tid & 7;        // uint4 slot within row (8 bf16 cols)
    int rslot = tid >> 3;    // 0..31
    int gr1 = row0 + rslot;
    int gr2 = row0 + rslot + 32;
    bool val1 = gr1 < N_NODES, val2 = gr2 < N_NODES;

    float a0 = 0.f, a1 = 0.f, a2 = 0.f, a3 = 0.f;
    float a4 = 0.f, a5 = 0.f, a6 = 0.f, a7 = 0.f;
    float d0 = 0.f, d1 = 0.f, d2 = 0.f, d3 = 0.f;
    float d4 = 0.f, d5 = 0.f, d6 = 0.f, d7 = 0.f;
    if (val1) {
        uint4 sv = xb4[(size_t)gr1 * 8 + c8];
        ACC8(sv, a0, a1, a2, a3, a4, a5, a6, a7)
    }
    if (val2) {
        uint4 sv = xb4[(size_t)gr2 * 8 + c8];
        ACC8(sv, d0, d1, d2, d3, d4, d5, d6, d7)
    }
    int beg1 = val1 ? rbeg[gr1] : 0, end1 = val1 ? rend[gr1] : 0;
    int beg2 = val2 ? rbeg[gr2] : 0, end2 = val2 ? rend[gr2] : 0;
    int len1 = end1 - beg1, len2 = end2 - beg2;
    int nmax = len1 > len2 ? len1 : len2;
    for (int o = 0; o < nmax; o += 8) {
        const int* p1 = (o < len1) ? (nbr + beg1 + o) : sent;
        const int* p2 = (o < len2) ? (nbr + beg2 + o) : sent;
        int4 ia1 = *reinterpret_cast<const int4*>(p1);
        int4 ib1 = *reinterpret_cast<const int4*>(p1 + 4);
        int4 ia2 = *reinterpret_cast<const int4*>(p2);
        int4 ib2 = *reinterpret_cast<const int4*>(p2 + 4);
        uint4 u0 = xb4[(size_t)ia1.x * 8 + c8];
        uint4 u1 = xb4[(size_t)ia1.y * 8 + c8];
        uint4 u2 = xb4[(size_t)ia1.z * 8 + c8];
        uint4 u3 = xb4[(size_t)ia1.w * 8 + c8];
        uint4 u4 = xb4[(size_t)ib1.x * 8 + c8];
        uint4 u5 = xb4[(size_t)ib1.y * 8 + c8];
        uint4 u6 = xb4[(size_t)ib1.z * 8 + c8];
        uint4 u7 = xb4[(size_t)ib1.w * 8 + c8];
        uint4 w0 = xb4[(size_t)ia2.x * 8 + c8];
        uint4 w1 = xb4[(size_t)ia2.y * 8 + c8];
        uint4 w2 = xb4[(size_t)ia2.z * 8 + c8];
        uint4 w3 = xb4[(size_t)ia2.w * 8 + c8];
        uint4 w4 = xb4[(size_t)ib2.x * 8 + c8];
        uint4 w5 = xb4[(size_t)ib2.y * 8 + c8];
        uint4 w6 = xb4[(size_t)ib2.z * 8 + c8];
        uint4 w7 = xb4[(size_t)ib2.w * 8 + c8];
        ACC8(u0, a0, a1, a2, a3, a4, a5, a6, a7)
        ACC8(u1, a0, a1, a2, a3, a4, a5, a6, a7)
        ACC8(u2, a0, a1, a2, a3, a4, a5, a6, a7)
        ACC8(u3, a0, a1, a2, a3, a4, a5, a6, a7)
        ACC8(u4, a0, a1, a2, a3, a4, a5, a6, a7)
        ACC8(u5, a0, a1, a2, a3, a4, a5, a6, a7)
        ACC8(u6, a0, a1, a2, a3, a4, a5, a6, a7)
        ACC8(u7, a0, a1, a2, a3, a4, a5, a6, a7)
        ACC8(w0, d0, d1, d2, d3, d4, d5, d6, d7)
        ACC8(w1, d0, d1, d2, d3, d4, d5, d6, d7)
        ACC8(w2, d0, d1, d2, d3, d4, d5, d6, d7)
        ACC8(w3, d0, d1, d2, d3, d4, d5, d6, d7)
        ACC8(w4, d0, d1, d2, d3, d4, d5, d6, d7)
        ACC8(w5, d0, d1, d2, d3, d4, d5, d6, d7)
        ACC8(w6, d0, d1, d2, d3, d4, d5, d6, d7)
        ACC8(w7, d0, d1, d2, d3, d4, d5, d6, d7)
    }
    {
        uint4 o1;
        o1.x = bf_pack(a0, a1); o1.y = bf_pack(a2, a3);
        o1.z = bf_pack(a4, a5); o1.w = bf_pack(a6, a7);
        *reinterpret_cast<uint4*>(&sA[rslot][c8 * 8]) = o1;
        uint4 o2;
        o2.x = bf_pack(d0, d1); o2.y = bf_pack(d2, d3);
        o2.z = bf_pack(d4, d5); o2.w = bf_pack(d6, d7);
        *reinterpret_cast<uint4*>(&sA[rslot + 32][c8 * 8]) = o2;
    }
    __syncthreads();

    // MFMA GEMM: wave w owns rows [16w,16w+16); 4 col-tiles x 2 K-chunks
    int w = tid >> 6;
    int l = tid & 63;
    int lr = l & 15;         // A-row within tile / D-col
    int lk = l >> 4;         // k-group / D row-group
    f32x4 acc[4];
    #pragma unroll
    for (int ct = 0; ct < 4; ++ct) {
        float b = b1[ct * 16 + lr];
        acc[ct] = (f32x4){b, b, b, b};
    }
    #pragma unroll
    for (int ct = 0; ct < 4; ++ct) {
        #pragma unroll
        for (int kc = 0; kc < 2; ++kc) {
            bf16x8 av = *reinterpret_cast<const bf16x8*>(&sA[w * 16 + lr][kc * 32 + lk * 8]);
            bf16x8 bv = *reinterpret_cast<const bf16x8*>(&sW[ct * 16 + lr][kc * 32 + lk * 8]);
            acc[ct] = __builtin_amdgcn_mfma_f32_16x16x32_bf16(av, bv, acc[ct], 0, 0, 0);
        }
    }

    // epilogue: h16 write + BN stats from accumulators
    float s4[4] = {0.f, 0.f, 0.f, 0.f};
    float q4[4] = {0.f, 0.f, 0.f, 0.f};
    #pragma unroll
    for (int ct = 0; ct < 4; ++ct) {
        #pragma unroll
        for (int r = 0; r < 4; ++r) {
            int row = row0 + w * 16 + lk * 4 + r;
            float v = acc[ct][r];
            if (row < N_NODES) {
                h16[(size_t)row * 64 + ct * 16 + lr] = bf1(v);
                s4[ct] += v;
                q4[ct] += v * v;
            }
        }
    }
    __syncthreads();                       // all MFMA reads of sW done
    float* scr = reinterpret_cast<float*>(&sW[0][0]);   // 2048 f32 <= 2304 avail
    int g16 = w * 4 + lk;                  // 0..15
    #pragma unroll
    for (int ct = 0; ct < 4; ++ct) {
        scr[g16 * 64 + ct * 16 + lr] = s4[ct];
        scr[1024 + g16 * 64 + ct * 16 + lr] = q4[ct];
    }
    __syncthreads();
    if (tid < 64) {
        float s = 0.f, q = 0.f;
        #pragma unroll
        for (int r2 = 0; r2 < 16; ++r2) {
            s += scr[r2 * 64 + tid];
            q += scr[1024 + r2 * 64 + tid];
        }
        unsafeAtomicAdd(&stats[tid], s);
        unsafeAtomicAdd(&stats[64 + tid], q);
    }
}

// -- MFMA GEMM2 + pool (64 rows/block); xout write skipped when null -------
__global__ __launch_bounds__(256) void gemm2_pool_kernel(
    const unsigned short* __restrict__ h16, const float* __restrict__ stats,
    const float* __restrict__ gamma, const float* __restrict__ beta,
    const float* __restrict__ W2, const float* __restrict__ b2,
    const int* __restrict__ batch, float* __restrict__ pooled,
    unsigned short* __restrict__ xout) {
    __shared__ unsigned short sA[64][72];
    __shared__ unsigned short sW[64][72];
    int tid = threadIdx.x;
    int row0 = blockIdx.x * 64;

    // stage W2 transposed to [col][k]
    for (int i = tid; i < 1024; i += 256) {
        int k = i >> 4, cb = (i & 15) * 4;
        float4 w = reinterpret_cast<const float4*>(W2)[i];
        sW[cb + 0][k] = bf1(w.x);
        sW[cb + 1][k] = bf1(w.y);
        sW[cb + 2][k] = bf1(w.z);
        sW[cb + 3][k] = bf1(w.w);
    }

    // per-thread BN scale/shift for its fixed 8 staging columns
    int c8 = tid & 7;
    float scv[8], shv[8];
    #pragma unroll
    for (int k = 0; k < 8; ++k) {
        int col = c8 * 8 + k;
        float mu = stats[col] * (1.0f / N_NODES);
        float var = stats[64 + col] * (1.0f / N_NODES) - mu * mu;
        scv[k] = gamma[col] * rsqrtf(var + BN_EPS);
        shv[k] = beta[col] - mu * scv[k];
    }

    const uint4* h4 = reinterpret_cast<const uint4*>(h16);
    for (int i = tid; i < 512; i += 256) {
        int r = i >> 3;                    // (i&7) == c8 since 256 % 8 == 0
        int gr = row0 + r;
        float o[8] = {0.f, 0.f, 0.f, 0.f, 0.f, 0.f, 0.f, 0.f};
        if (gr < N_NODES) {
            uint4 v = h4[(size_t)gr * 8 + c8];
            float f[8] = {lo16(v.x), hi16(v.x), lo16(v.y), hi16(v.y),
                          lo16(v.z), hi16(v.z), lo16(v.w), hi16(v.w)};
            #pragma unroll
            for (int k = 0; k < 8; ++k)
                o[k] = fmaxf(fmaf(f[k], scv[k], shv[k]), 0.f);
        }
        uint4 p;
        p.x = bf_pack(o[0], o[1]); p.y = bf_pack(o[2], o[3]);
        p.z = bf_pack(o[4], o[5]); p.w = bf_pack(o[6], o[7]);
        *reinterpret_cast<uint4*>(&sA[r][c8 * 8]) = p;
    }
    __syncthreads();

    int w = tid >> 6;
    int l = tid & 63;
    int lr = l & 15;
    int lk = l >> 4;
    f32x4 acc[4];
    #pragma unroll
    for (int ct = 0; ct < 4; ++ct) {
        float b = b2[ct * 16 + lr];
        acc[ct] = (f32x4){b, b, b, b};
    }
    #pragma unroll
    for (int ct = 0; ct < 4; ++ct) {
        #pragma unroll
        for (int kc = 0; kc < 2; ++kc) {
            bf16x8 av = *reinterpret_cast<const bf16x8*>(&sA[w * 16 + lr][kc * 32 + lk * 8]);
            bf16x8 bv = *reinterpret_cast<const bf16x8*>(&sW[ct * 16 + lr][kc * 32 + lk * 8]);
            acc[ct] = __builtin_amdgcn_mfma_f32_16x16x32_bf16(av, bv, acc[ct], 0, 0, 0);
        }
    }

    // write xout (bf16) unless last layer
    if (xout) {
        #pragma unroll
        for (int ct = 0; ct < 4; ++ct) {
            #pragma unroll
            for (int r = 0; r < 4; ++r) {
                int row = row0 + w * 16 + lk * 4 + r;
                if (row < N_NODES)
                    xout[(size_t)row * 64 + ct * 16 + lr] = bf1(acc[ct][r]);
            }
        }
    }

    // pool: single-graph block -> LDS reduce + 1 atomic/col; else run-length
    int lastrow = row0 + 63; if (lastrow >= N_NODES) lastrow = N_NODES - 1;
    int b0 = batch[row0 < N_NODES ? row0 : N_NODES - 1], bL = batch[lastrow];
    int g16 = w * 4 + lk;
    if (b0 == bL) {
        float ps[4] = {0.f, 0.f, 0.f, 0.f};
        #pragma unroll
        for (int ct = 0; ct < 4; ++ct) {
            #pragma unroll
            for (int r = 0; r < 4; ++r) {
                int row = row0 + w * 16 + lk * 4 + r;
                if (row < N_NODES) ps[ct] += acc[ct][r];
            }
        }
        __syncthreads();                   // MFMA reads of sW done
        float* scr = reinterpret_cast<float*>(&sW[0][0]);
        #pragma unroll
        for (int ct = 0; ct < 4; ++ct)
            scr[g16 * 64 + ct * 16 + lr] = ps[ct];
        __syncthreads();
        if (tid < 64) {
            float s = 0.f;
            #pragma unroll
            for (int r2 = 0; r2 < 16; ++r2) s += scr[r2 * 64 + tid];
            unsafeAtomicAdd(&pooled[b0 * 64 + tid], s);
        }
    } else {
        #pragma unroll
        for (int ct = 0; ct < 4; ++ct) {
            float pacc = 0.f;
            int curb = -1;
            int col = ct * 16 + lr;
            #pragma unroll
            for (int r = 0; r < 4; ++r) {
                int row = row0 + w * 16 + lk * 4 + r;
                if (row < N_NODES) {
                    int b = batch[row];
                    if (b != curb) {
                        if (curb >= 0) unsafeAtomicAdd(&pooled[curb * 64 + col], pacc);
                        curb = b;
                        pacc = 0.f;
                    }
                    pacc += acc[ct][r];
                }
            }
            if (curb >= 0) unsafeAtomicAdd(&pooled[curb * 64 + col], pacc);
        }
    }
}

// ------- output (all layers): score = sum_l pooled_l @ Wout_l + bout_l ----
__global__ void out3_kernel(const float* __restrict__ pooled3,
                            const float* __restrict__ Wout,
                            const float* __restrict__ bout,
                            float* __restrict__ score) {
    int idx = blockIdx.x * blockDim.x + threadIdx.x;
    if (idx >= G_GRAPHS * OUT_F) return;
    int g = idx / OUT_F;
    int o = idx - g * OUT_F;
    float acc = 0.f;
    for (int l = 0; l < L_LAYERS; ++l) {
        acc += bout[l * OUT_F + o];
        const float* pl = pooled3 + (size_t)l * G_GRAPHS * 64 + g * 64;
        const float* wl = Wout + l * 64 * OUT_F;
        #pragma unroll
        for (int k = 0; k < 64; ++k) acc += pl[k] * wl[k * OUT_F + o];
    }
    score[idx] = acc;
}

extern "C" void kernel_launch(void* const* d_in, const int* in_sizes, int n_in,
                              void* d_out, int out_size, void* d_ws, size_t ws_size,
                              hipStream_t stream) {
    const float* x     = (const float*)d_in[0];
    const int*   ei    = (const int*)d_in[1];
    const int*   batch = (const int*)d_in[2];
    const float* W1    = (const float*)d_in[3];
    const float* b1    = (const float*)d_in[4];
    const float* gamma = (const float*)d_in[5];
    const float* beta  = (const float*)d_in[6];
    const float* W2    = (const float*)d_in[7];
    const float* b2    = (const float*)d_in[8];
    const float* Wout  = (const float*)d_in[9];
    const float* bout  = (const float*)d_in[10];
    float* out = (float*)d_out;

    unsigned short* H16 = (unsigned short*)d_ws;             // N*64 bf16
    uint*  XBF    = (uint*)(H16 + (size_t)N_NODES * 64);     // (N+1)*32 uints
    float* stats3 = (float*)(XBF + (size_t)(N_NODES + 1) * 32);  // 3*128
    float* pooled3= stats3 + 3 * 128;                        // 3*G*64
    int*   gcur   = (int*)(pooled3 + (size_t)3 * G_GRAPHS * 64); // 8
    int*   sent   = gcur + 8;                                // 16
    int*   scur   = sent + 16;                               // 784 (pad)
    int*   rbeg   = scur + 784;                              // N
    int*   rend   = rbeg + N_NODES;                          // N
    int*   nbr    = rend + N_NODES;                          // NSTRIPE*SNBR + 16
    int2*  epair1 = (int2*)(nbr + (size_t)NSTRIPE * SNBR + 16);  // 8*BCAP pairs
    int2*  epair2 = epair1 + (size_t)8 * BCAP;               // NSTRIPE*SCAP pairs

    const int* src = ei;
    const int* dst = ei + E_EDGES;

    // zero all per-layer stats+pooled in one shot
    (void)hipMemsetAsync(stats3, 0, (3 * 128 + (size_t)3 * G_GRAPHS * 64) * sizeof(float), stream);

    init_kernel<<<(NSTRIPE + 255) / 256, 256, 0, stream>>>(gcur, scur, sent);
    fillA_kernel<<<NCHUNK, 256, 0, stream>>>(src, dst, gcur, epair1);
    fillB2_kernel<<<FB_GRID, 256, 0, stream>>>(epair1, gcur, scur, epair2);
    fillC2_kernel<<<NSTRIPE, 256, 0, stream>>>(epair2, scur, rbeg, rend, nbr);
    tobf_kernel<<<(N_NODES * 8 + 255) / 256, 256, 0, stream>>>(x, XBF);

    int nb = (N_NODES + 63) / 64;

    for (int l = 0; l < L_LAYERS; ++l) {
        float* stats = stats3 + l * 128;
        float* pooled = pooled3 + (size_t)l * G_GRAPHS * 64;
        gemm1_fused_kernel<<<nb, 256, 0, stream>>>(XBF, rbeg, rend, nbr, sent,
            W1 + l * 64 * 64, b1 + l * 64, H16, stats);
        unsigned short* xout = (l == L_LAYERS - 1) ? (unsigned short*)nullptr
                                                   : (unsigned short*)XBF;
        gemm2_pool_kernel<<<nb, 256, 0, stream>>>(H16, stats,
            gamma + l * 64, beta + l * 64, W2 + l * 64 * 64, b2 + l * 64, batch,
            pooled, xout);
    }
    out3_kernel<<<(G_GRAPHS * OUT_F + 127) / 128, 128, 0, stream>>>(
        pooled3, Wout, bout, out);
}

// Round 21
// 310.180 us; speedup vs baseline: 1.0697x; 1.0697x over previous
//
#include <hip/hip_runtime.h>

typedef unsigned int uint;
typedef short bf16x8 __attribute__((ext_vector_type(8)));
typedef float f32x4 __attribute__((ext_vector_type(4)));

#define N_NODES 100000
#define E_EDGES 1600000
#define L_LAYERS 3
#define G_GRAPHS 128
#define OUT_F 10
#define BN_EPS 1e-5f

#define BSHIFT 7                          // 128-node stripes
#define NSTRIPE ((N_NODES + 127) >> 7)    // 782
#define CHUNK 2048
#define NCHUNK ((E_EDGES + CHUNK - 1) / CHUNK)   // 782
#define PAD8(d) (((d) + 7) & ~7)
#define BCAP (2048 * 103)                 // per-XCD queue capacity (pairs)
#define FB_GRID (103 * 8)
#define SCAP 2560                         // per-stripe queue capacity (pairs)
#define SNBR 3584                         // per-stripe nbr region (ints)

// bf16 pack (RTNE) / unpack helpers
__device__ __forceinline__ uint bf_pack(float a, float b) {
    uint ua = __float_as_uint(a);
    ua = (ua + 0x7fffu + ((ua >> 16) & 1u)) >> 16;
    uint ub = __float_as_uint(b);
    ub = (ub + 0x7fffu + ((ub >> 16) & 1u)) >> 16;
    return ua | (ub << 16);
}
__device__ __forceinline__ unsigned short bf1(float a) {
    uint ua = __float_as_uint(a);
    return (unsigned short)((ua + 0x7fffu + ((ua >> 16) & 1u)) >> 16);
}
__device__ __forceinline__ float lo16(uint u) { return __uint_as_float(u << 16); }
__device__ __forceinline__ float hi16(uint u) { return __uint_as_float(u & 0xffff0000u); }

// -------------------- init queue cursors ----------------------------------
__global__ __launch_bounds__(256) void init_kernel(int* __restrict__ gcur,
                                                   int* __restrict__ scur) {
    int t = blockIdx.x * 256 + threadIdx.x;
    if (t < 8) gcur[t] = t * BCAP;
    if (t < NSTRIPE) scur[t] = t * SCAP;
}

// ---- fill pass A: bin edges into 8 per-XCD queues (single read of ei) ----
__global__ __launch_bounds__(256) void fillA_kernel(
    const int* __restrict__ src, const int* __restrict__ dst,
    int* __restrict__ gcur, int2* __restrict__ epair) {
    __shared__ int lcnt[8];
    __shared__ int lbase[8];
    int tid = threadIdx.x;
    int base = blockIdx.x * CHUNK;
    if (tid < 8) lcnt[tid] = 0;
    __syncthreads();

    int sd[8], ss[8], bk[8], off[8];
    #pragma unroll
    for (int it = 0; it < 8; ++it) {
        int e = base + it * 256 + tid;
        bk[it] = -1;
        if (e < E_EDGES) {
            sd[it] = dst[e];
            ss[it] = src[e];
            bk[it] = (sd[it] >> BSHIFT) & 7;
            off[it] = atomicAdd(&lcnt[bk[it]], 1);
        }
    }
    __syncthreads();
    if (tid < 8) lbase[tid] = atomicAdd(&gcur[tid], lcnt[tid]);
    __syncthreads();
    #pragma unroll
    for (int it = 0; it < 8; ++it) {
        if (bk[it] >= 0)
            epair[lbase[bk[it]] + off[it]] = make_int2(ss[it], sd[it]);
    }
}

// ---- fill pass B2: bin XCD queue by stripe (98 buckets per XCD) ----------
__global__ __launch_bounds__(256) void fillB2_kernel(
    const int2* __restrict__ epair1, const int* __restrict__ gcur,
    int* __restrict__ scur, int2* __restrict__ epair2) {
    __shared__ int lcnt[98];
    __shared__ int lbase[98];
    int tid = threadIdx.x;
    int g = blockIdx.x & 7;
    int c = blockIdx.x >> 3;
    int ebeg = g * BCAP + c * CHUNK;
    int eend = gcur[g];
    if (tid < 98) lcnt[tid] = 0;
    __syncthreads();

    int2 pp[8]; int bk[8], off[8];
    #pragma unroll
    for (int it = 0; it < 8; ++it) {
        int i = ebeg + it * 256 + tid;
        bk[it] = -1;
        if (i < eend) {
            pp[it] = epair1[i];
            bk[it] = pp[it].y >> 10;               // fine bucket within XCD
            off[it] = atomicAdd(&lcnt[bk[it]], 1);
        }
    }
    __syncthreads();
    if (tid < 98 && lcnt[tid] > 0)
        lbase[tid] = atomicAdd(&scur[(tid << 3) | g], lcnt[tid]);
    __syncthreads();
    #pragma unroll
    for (int it = 0; it < 8; ++it) {
        if (bk[it] >= 0)
            epair2[lbase[bk[it]] + off[it]] = pp[it];
    }
}

// ---- fill pass C2: per-stripe degree-count + scan + place + seq write ----
__global__ __launch_bounds__(256) void fillC2_kernel(
    const int2* __restrict__ epair2, const int* __restrict__ scur,
    int* __restrict__ rbeg, int* __restrict__ rend, int* __restrict__ nbr) {
    __shared__ int cnt[128];
    __shared__ int loc[128];
    __shared__ int off[128];
    __shared__ int buf[SNBR];
    __shared__ int stotal;
    int s = blockIdx.x;
    int tid = threadIdx.x;
    int node0 = s << 7;
    int qbeg = s * SCAP;
    int qend = scur[s];                    // base + count after fillB2
    if (tid < 128) cnt[tid] = 0;
    __syncthreads();

    for (int i = qbeg + tid; i < qend; i += 256)
        atomicAdd(&cnt[epair2[i].y & 127], 1);
    __syncthreads();

    int v = (tid < 128) ? PAD8(cnt[tid]) : 0;
    if (tid < 128) loc[tid] = v;
    __syncthreads();
    for (int o = 1; o < 128; o <<= 1) {
        int u = (tid < 128 && tid >= o) ? loc[tid - o] : 0;
        __syncthreads();
        if (tid < 128) loc[tid] += u;
        __syncthreads();
    }
    int sbase = s * SNBR;
    if (tid < 128) {
        int ex = loc[tid] - v;             // exclusive prefix
        off[tid] = ex;
        int node = node0 + tid;
        if (node < N_NODES) {
            rbeg[node] = sbase + ex;
            rend[node] = sbase + ex + v;   // padded end
        }
    }
    if (tid == 0) stotal = loc[127];
    __syncthreads();
    int total = stotal;

    for (int i = tid; i < total; i += 256) buf[i] = N_NODES;   // sentinels
    __syncthreads();

    for (int i = qbeg + tid; i < qend; i += 256) {
        int2 p = epair2[i];
        int pos = atomicAdd(&off[p.y & 127], 1);
        buf[pos] = p.x;
    }
    __syncthreads();

    for (int i = tid * 4; i < total; i += 1024)
        *reinterpret_cast<int4*>(nbr + sbase + i) = *reinterpret_cast<const int4*>(buf + i);
}

// -------------------- x f32 -> bf16 (layer 0 only) ------------------------
__global__ __launch_bounds__(256) void tobf_kernel(const float* __restrict__ x,
                                                   uint* __restrict__ xbf) {
    int i = blockIdx.x * 256 + threadIdx.x;   // N*8 threads, 8 floats each
    if (i < N_NODES * 8) {
        float4 a = reinterpret_cast<const float4*>(x)[i * 2];
        float4 b = reinterpret_cast<const float4*>(x)[i * 2 + 1];
        uint4 o;
        o.x = bf_pack(a.x, a.y);
        o.y = bf_pack(a.z, a.w);
        o.z = bf_pack(b.x, b.y);
        o.w = bf_pack(b.z, b.w);
        reinterpret_cast<uint4*>(xbf)[i] = o;
    }
    if (i < 8) reinterpret_cast<uint4*>(xbf)[N_NODES * 8 + i] = make_uint4(0, 0, 0, 0);
}

// ------- fused gather(bf16, padded CSR, idx-prefetch) + MFMA GEMM1 --------
__global__ __launch_bounds__(256) void gemm1_fused_kernel(
    const uint* __restrict__ xbf, const int* __restrict__ rbeg,
    const int* __restrict__ rend, const int* __restrict__ nbr,
    const float* __restrict__ W1, const float* __restrict__ b1,
    unsigned short* __restrict__ h16, float* __restrict__ stats) {
    __shared__ unsigned short sA[64][72];        // bf16 agg tile (pad: 2-way alias)
    __shared__ unsigned short sW[64][72];        // bf16 W^T [col][k]
    int tid = threadIdx.x;
    int row0 = blockIdx.x * 64;

    // stage W1 transposed to [col][k]
    for (int i = tid; i < 1024; i += 256) {
        int k = i >> 4, cb = (i & 15) * 4;
        float4 w = reinterpret_cast<const float4*>(W1)[i];
        sW[cb + 0][k] = bf1(w.x);
        sW[cb + 1][k] = bf1(w.y);
        sW[cb + 2][k] = bf1(w.z);
        sW[cb + 3][k] = bf1(w.w);
    }

    const uint4* xb4 = reinterpret_cast<const uint4*>(xbf);
    int c8 = tid & 7;        // uint4 slot within row (8 bf16 cols)
    int rslot = tid >> 3;    // 32 rows per pass
    for (int rr = 0; rr < 2; ++rr) {
        int r = rslot + 32 * rr;
        int gr = row0 + r;
        float a0 = 0.f, a1 = 0.f, a2 = 0.f, a3 = 0.f;
        float a4 = 0.f, a5 = 0.f, a6 = 0.f, a7 = 0.f;
        if (gr < N_NODES) {
            uint4 sv = xb4[(size_t)gr * 8 + c8];
            a0 = lo16(sv.x); a1 = hi16(sv.x); a2 = lo16(sv.y); a3 = hi16(sv.y);
            a4 = lo16(sv.z); a5 = hi16(sv.z); a6 = lo16(sv.w); a7 = hi16(sv.w);
            int beg = rbeg[gr], end = rend[gr];
            int4 ia = *reinterpret_cast<const int4*>(nbr + beg);
            int4 ib = *reinterpret_cast<const int4*>(nbr + beg + 4);
            for (int j = beg; j < end; j += 8) {
                int4 ian = *reinterpret_cast<const int4*>(nbr + j + 8);
                int4 ibn = *reinterpret_cast<const int4*>(nbr + j + 12);
                uint4 v0 = xb4[(size_t)ia.x * 8 + c8];
                uint4 v1 = xb4[(size_t)ia.y * 8 + c8];
                uint4 v2 = xb4[(size_t)ia.z * 8 + c8];
                uint4 v3 = xb4[(size_t)ia.w * 8 + c8];
                uint4 v4 = xb4[(size_t)ib.x * 8 + c8];
                uint4 v5 = xb4[(size_t)ib.y * 8 + c8];
                uint4 v6 = xb4[(size_t)ib.z * 8 + c8];
                uint4 v7 = xb4[(size_t)ib.w * 8 + c8];
                a0 += lo16(v0.x); a1 += hi16(v0.x); a2 += lo16(v0.y); a3 += hi16(v0.y);
                a4 += lo16(v0.z); a5 += hi16(v0.z); a6 += lo16(v0.w); a7 += hi16(v0.w);
                a0 += lo16(v1.x); a1 += hi16(v1.x); a2 += lo16(v1.y); a3 += hi16(v1.y);
                a4 += lo16(v1.z); a5 += hi16(v1.z); a6 += lo16(v1.w); a7 += hi16(v1.w);
                a0 += lo16(v2.x); a1 += hi16(v2.x); a2 += lo16(v2.y); a3 += hi16(v2.y);
                a4 += lo16(v2.z); a5 += hi16(v2.z); a6 += lo16(v2.w); a7 += hi16(v2.w);
                a0 += lo16(v3.x); a1 += hi16(v3.x); a2 += lo16(v3.y); a3 += hi16(v3.y);
                a4 += lo16(v3.z); a5 += hi16(v3.z); a6 += lo16(v3.w); a7 += hi16(v3.w);
                a0 += lo16(v4.x); a1 += hi16(v4.x); a2 += lo16(v4.y); a3 += hi16(v4.y);
                a4 += lo16(v4.z); a5 += hi16(v4.z); a6 += lo16(v4.w); a7 += hi16(v4.w);
                a0 += lo16(v5.x); a1 += hi16(v5.x); a2 += lo16(v5.y); a3 += hi16(v5.y);
                a4 += lo16(v5.z); a5 += hi16(v5.z); a6 += lo16(v5.w); a7 += hi16(v5.w);
                a0 += lo16(v6.x); a1 += hi16(v6.x); a2 += lo16(v6.y); a3 += hi16(v6.y);
                a4 += lo16(v6.z); a5 += hi16(v6.z); a6 += lo16(v6.w); a7 += hi16(v6.w);
                a0 += lo16(v7.x); a1 += hi16(v7.x); a2 += lo16(v7.y); a3 += hi16(v7.y);
                a4 += lo16(v7.z); a5 += hi16(v7.z); a6 += lo16(v7.w); a7 += hi16(v7.w);
                ia = ian; ib = ibn;
            }
        }
        uint4 o;
        o.x = bf_pack(a0, a1); o.y = bf_pack(a2, a3);
        o.z = bf_pack(a4, a5); o.w = bf_pack(a6, a7);
        *reinterpret_cast<uint4*>(&sA[r][c8 * 8]) = o;
    }
    __syncthreads();

    // MFMA GEMM: wave w owns rows [16w,16w+16); 4 col-tiles x 2 K-chunks
    int w = tid >> 6;
    int l = tid & 63;
    int lr = l & 15;         // A-row within tile / D-col
    int lk = l >> 4;         // k-group / D row-group
    f32x4 acc[4];
    #pragma unroll
    for (int ct = 0; ct < 4; ++ct) {
        float b = b1[ct * 16 + lr];
        acc[ct] = (f32x4){b, b, b, b};
    }
    #pragma unroll
    for (int ct = 0; ct < 4; ++ct) {
        #pragma unroll
        for (int kc = 0; kc < 2; ++kc) {
            bf16x8 av = *reinterpret_cast<const bf16x8*>(&sA[w * 16 + lr][kc * 32 + lk * 8]);
            bf16x8 bv = *reinterpret_cast<const bf16x8*>(&sW[ct * 16 + lr][kc * 32 + lk * 8]);
            acc[ct] = __builtin_amdgcn_mfma_f32_16x16x32_bf16(av, bv, acc[ct], 0, 0, 0);
        }
    }

    // epilogue: h16 write + BN stats from accumulators
    float s4[4] = {0.f, 0.f, 0.f, 0.f};   // per-ct col partial sums
    float q4[4] = {0.f, 0.f, 0.f, 0.f};
    #pragma unroll
    for (int ct = 0; ct < 4; ++ct) {
        #pragma unroll
        for (int r = 0; r < 4; ++r) {
            int row = row0 + w * 16 + lk * 4 + r;
            float v = acc[ct][r];
            if (row < N_NODES) {
                h16[(size_t)row * 64 + ct * 16 + lr] = bf1(v);
                s4[ct] += v;
                q4[ct] += v * v;
            }
        }
    }
    __syncthreads();                       // all MFMA reads of sW done
    float* scr = reinterpret_cast<float*>(&sW[0][0]);   // 2048 f32 <= 2304 avail
    int g16 = w * 4 + lk;                  // 0..15
    #pragma unroll
    for (int ct = 0; ct < 4; ++ct) {
        scr[g16 * 64 + ct * 16 + lr] = s4[ct];
        scr[1024 + g16 * 64 + ct * 16 + lr] = q4[ct];
    }
    __syncthreads();
    if (tid < 64) {
        float s = 0.f, q = 0.f;
        #pragma unroll
        for (int r2 = 0; r2 < 16; ++r2) {
            s += scr[r2 * 64 + tid];
            q += scr[1024 + r2 * 64 + tid];
        }
        unsafeAtomicAdd(&stats[tid], s);
        unsafeAtomicAdd(&stats[64 + tid], q);
    }
}

// -- MFMA GEMM2 + pool (64 rows/block); xout write skipped when null -------
__global__ __launch_bounds__(256) void gemm2_pool_kernel(
    const unsigned short* __restrict__ h16, const float* __restrict__ stats,
    const float* __restrict__ gamma, const float* __restrict__ beta,
    const float* __restrict__ W2, const float* __restrict__ b2,
    const int* __restrict__ batch, float* __restrict__ pooled,
    unsigned short* __restrict__ xout) {
    __shared__ unsigned short sA[64][72];
    __shared__ unsigned short sW[64][72];
    int tid = threadIdx.x;
    int row0 = blockIdx.x * 64;

    // stage W2 transposed to [col][k]
    for (int i = tid; i < 1024; i += 256) {
        int k = i >> 4, cb = (i & 15) * 4;
        float4 w = reinterpret_cast<const float4*>(W2)[i];
        sW[cb + 0][k] = bf1(w.x);
        sW[cb + 1][k] = bf1(w.y);
        sW[cb + 2][k] = bf1(w.z);
        sW[cb + 3][k] = bf1(w.w);
    }

    // per-thread BN scale/shift for its fixed 8 staging columns
    int c8 = tid & 7;
    float scv[8], shv[8];
    #pragma unroll
    for (int k = 0; k < 8; ++k) {
        int col = c8 * 8 + k;
        float mu = stats[col] * (1.0f / N_NODES);
        float var = stats[64 + col] * (1.0f / N_NODES) - mu * mu;
        scv[k] = gamma[col] * rsqrtf(var + BN_EPS);
        shv[k] = beta[col] - mu * scv[k];
    }

    const uint4* h4 = reinterpret_cast<const uint4*>(h16);
    for (int i = tid; i < 512; i += 256) {
        int r = i >> 3;                    // (i&7) == c8 since 256 % 8 == 0
        int gr = row0 + r;
        float o[8] = {0.f, 0.f, 0.f, 0.f, 0.f, 0.f, 0.f, 0.f};
        if (gr < N_NODES) {
            uint4 v = h4[(size_t)gr * 8 + c8];
            float f[8] = {lo16(v.x), hi16(v.x), lo16(v.y), hi16(v.y),
                          lo16(v.z), hi16(v.z), lo16(v.w), hi16(v.w)};
            #pragma unroll
            for (int k = 0; k < 8; ++k)
                o[k] = fmaxf(fmaf(f[k], scv[k], shv[k]), 0.f);
        }
        uint4 p;
        p.x = bf_pack(o[0], o[1]); p.y = bf_pack(o[2], o[3]);
        p.z = bf_pack(o[4], o[5]); p.w = bf_pack(o[6], o[7]);
        *reinterpret_cast<uint4*>(&sA[r][c8 * 8]) = p;
    }
    __syncthreads();

    int w = tid >> 6;
    int l = tid & 63;
    int lr = l & 15;
    int lk = l >> 4;
    f32x4 acc[4];
    #pragma unroll
    for (int ct = 0; ct < 4; ++ct) {
        float b = b2[ct * 16 + lr];
        acc[ct] = (f32x4){b, b, b, b};
    }
    #pragma unroll
    for (int ct = 0; ct < 4; ++ct) {
        #pragma unroll
        for (int kc = 0; kc < 2; ++kc) {
            bf16x8 av = *reinterpret_cast<const bf16x8*>(&sA[w * 16 + lr][kc * 32 + lk * 8]);
            bf16x8 bv = *reinterpret_cast<const bf16x8*>(&sW[ct * 16 + lr][kc * 32 + lk * 8]);
            acc[ct] = __builtin_amdgcn_mfma_f32_16x16x32_bf16(av, bv, acc[ct], 0, 0, 0);
        }
    }

    // write xout (bf16) unless last layer
    if (xout) {
        #pragma unroll
        for (int ct = 0; ct < 4; ++ct) {
            #pragma unroll
            for (int r = 0; r < 4; ++r) {
                int row = row0 + w * 16 + lk * 4 + r;
                if (row < N_NODES)
                    xout[(size_t)row * 64 + ct * 16 + lr] = bf1(acc[ct][r]);
            }
        }
    }

    // pool: single-graph block -> LDS reduce + 1 atomic/col; else run-length
    int lastrow = row0 + 63; if (lastrow >= N_NODES) lastrow = N_NODES - 1;
    int b0 = batch[row0 < N_NODES ? row0 : N_NODES - 1], bL = batch[lastrow];
    int g16 = w * 4 + lk;
    if (b0 == bL) {
        float ps[4] = {0.f, 0.f, 0.f, 0.f};
        #pragma unroll
        for (int ct = 0; ct < 4; ++ct) {
            #pragma unroll
            for (int r = 0; r < 4; ++r) {
                int row = row0 + w * 16 + lk * 4 + r;
                if (row < N_NODES) ps[ct] += acc[ct][r];
            }
        }
        __syncthreads();                   // MFMA reads of sW done
        float* scr = reinterpret_cast<float*>(&sW[0][0]);
        #pragma unroll
        for (int ct = 0; ct < 4; ++ct)
            scr[g16 * 64 + ct * 16 + lr] = ps[ct];
        __syncthreads();
        if (tid < 64) {
            float s = 0.f;
            #pragma unroll
            for (int r2 = 0; r2 < 16; ++r2) s += scr[r2 * 64 + tid];
            unsafeAtomicAdd(&pooled[b0 * 64 + tid], s);
        }
    } else {
        #pragma unroll
        for (int ct = 0; ct < 4; ++ct) {
            float pacc = 0.f;
            int curb = -1;
            int col = ct * 16 + lr;
            #pragma unroll
            for (int r = 0; r < 4; ++r) {
                int row = row0 + w * 16 + lk * 4 + r;
                if (row < N_NODES) {
                    int b = batch[row];
                    if (b != curb) {
                        if (curb >= 0) unsafeAtomicAdd(&pooled[curb * 64 + col], pacc);
                        curb = b;
                        pacc = 0.f;
                    }
                    pacc += acc[ct][r];
                }
            }
            if (curb >= 0) unsafeAtomicAdd(&pooled[curb * 64 + col], pacc);
        }
    }
}

// ------- output (all layers): score = sum_l pooled_l @ Wout_l + bout_l ----
__global__ void out3_kernel(const float* __restrict__ pooled3,
                            const float* __restrict__ Wout,
                            const float* __restrict__ bout,
                            float* __restrict__ score) {
    int idx = blockIdx.x * blockDim.x + threadIdx.x;
    if (idx >= G_GRAPHS * OUT_F) return;
    int g = idx / OUT_F;
    int o = idx - g * OUT_F;
    float acc = 0.f;
    for (int l = 0; l < L_LAYERS; ++l) {
        acc += bout[l * OUT_F + o];
        const float* pl = pooled3 + (size_t)l * G_GRAPHS * 64 + g * 64;
        const float* wl = Wout + l * 64 * OUT_F;
        #pragma unroll
        for (int k = 0; k < 64; ++k) acc += pl[k] * wl[k * OUT_F + o];
    }
    score[idx] = acc;
}

extern "C" void kernel_launch(void* const* d_in, const int* in_sizes, int n_in,
                              void* d_out, int out_size, void* d_ws, size_t ws_size,
                              hipStream_t stream) {
    const float* x     = (const float*)d_in[0];
    const int*   ei    = (const int*)d_in[1];
    const int*   batch = (const int*)d_in[2];
    const float* W1    = (const float*)d_in[3];
    const float* b1    = (const float*)d_in[4];
    const float* gamma = (const float*)d_in[5];
    const float* beta  = (const float*)d_in[6];
    const float* W2    = (const float*)d_in[7];
    const float* b2    = (const float*)d_in[8];
    const float* Wout  = (const float*)d_in[9];
    const float* bout  = (const float*)d_in[10];
    float* out = (float*)d_out;

    unsigned short* H16 = (unsigned short*)d_ws;             // N*64 bf16
    uint*  XBF    = (uint*)(H16 + (size_t)N_NODES * 64);     // (N+1)*32 uints
    float* stats3 = (float*)(XBF + (size_t)(N_NODES + 1) * 32);  // 3*128
    float* pooled3= stats3 + 3 * 128;                        // 3*G*64
    int*   gcur   = (int*)(pooled3 + (size_t)3 * G_GRAPHS * 64); // 8
    int*   scur   = gcur + 8;                                // 784 (pad)
    int*   rbeg   = scur + 784;                              // N
    int*   rend   = rbeg + N_NODES;                          // N
    int*   nbr    = rend + N_NODES;                          // NSTRIPE*SNBR + 16
    int2*  epair1 = (int2*)(nbr + (size_t)NSTRIPE * SNBR + 16);  // 8*BCAP pairs
    int2*  epair2 = epair1 + (size_t)8 * BCAP;               // NSTRIPE*SCAP pairs

    const int* src = ei;
    const int* dst = ei + E_EDGES;

    // zero all per-layer stats+pooled in one shot
    (void)hipMemsetAsync(stats3, 0, (3 * 128 + (size_t)3 * G_GRAPHS * 64) * sizeof(float), stream);

    init_kernel<<<(NSTRIPE + 255) / 256, 256, 0, stream>>>(gcur, scur);
    fillA_kernel<<<NCHUNK, 256, 0, stream>>>(src, dst, gcur, epair1);
    fillB2_kernel<<<FB_GRID, 256, 0, stream>>>(epair1, gcur, scur, epair2);
    fillC2_kernel<<<NSTRIPE, 256, 0, stream>>>(epair2, scur, rbeg, rend, nbr);
    tobf_kernel<<<(N_NODES * 8 + 255) / 256, 256, 0, stream>>>(x, XBF);

    int nb = (N_NODES + 63) / 64;

    for (int l = 0; l < L_LAYERS; ++l) {
        float* stats = stats3 + l * 128;
        float* pooled = pooled3 + (size_t)l * G_GRAPHS * 64;
        gemm1_fused_kernel<<<nb, 256, 0, stream>>>(XBF, rbeg, rend, nbr,
            W1 + l * 64 * 64, b1 + l * 64, H16, stats);
        unsigned short* xout = (l == L_LAYERS - 1) ? (unsigned short*)nullptr
                                                   : (unsigned short*)XBF;
        gemm2_pool_kernel<<<nb, 256, 0, stream>>>(H16, stats,
            gamma + l * 64, beta + l * 64, W2 + l * 64 * 64, b2 + l * 64, batch,
            pooled, xout);
    }
    out3_kernel<<<(G_GRAPHS * OUT_F + 127) / 128, 128, 0, stream>>>(
        pooled3, Wout, bout, out);
}

// Round 22
// 308.054 us; speedup vs baseline: 1.0771x; 1.0069x over previous
//
#include <hip/hip_runtime.h>

typedef unsigned int uint;
typedef short bf16x8 __attribute__((ext_vector_type(8)));
typedef float f32x4 __attribute__((ext_vector_type(4)));

#define N_NODES 100000
#define E_EDGES 1600000
#define L_LAYERS 3
#define G_GRAPHS 128
#define OUT_F 10
#define BN_EPS 1e-5f

#define BSHIFT 7                          // 128-node stripes
#define NSTRIPE ((N_NODES + 127) >> 7)    // 782
#define CHUNK 2048
#define NCHUNK ((E_EDGES + CHUNK - 1) / CHUNK)   // 782
#define PAD8(d) (((d) + 7) & ~7)
#define BCAP (2048 * 103)                 // per-XCD queue capacity (pairs)
#define FB_GRID (103 * 8)
#define SCAP 2560                         // per-stripe queue capacity (pairs)
#define SNBR 3584                         // per-stripe nbr region (ints)

// bf16 pack (RTNE) / unpack helpers
__device__ __forceinline__ uint bf_pack(float a, float b) {
    uint ua = __float_as_uint(a);
    ua = (ua + 0x7fffu + ((ua >> 16) & 1u)) >> 16;
    uint ub = __float_as_uint(b);
    ub = (ub + 0x7fffu + ((ub >> 16) & 1u)) >> 16;
    return ua | (ub << 16);
}
__device__ __forceinline__ unsigned short bf1(float a) {
    uint ua = __float_as_uint(a);
    return (unsigned short)((ua + 0x7fffu + ((ua >> 16) & 1u)) >> 16);
}
__device__ __forceinline__ float lo16(uint u) { return __uint_as_float(u << 16); }
__device__ __forceinline__ float hi16(uint u) { return __uint_as_float(u & 0xffff0000u); }

// -------------------- init queue cursors ----------------------------------
__global__ __launch_bounds__(256) void init_kernel(int* __restrict__ gcur,
                                                   int* __restrict__ scur) {
    int t = blockIdx.x * 256 + threadIdx.x;
    if (t < 8) gcur[t] = t * BCAP;
    if (t < NSTRIPE) scur[t] = t * SCAP;
}

// ---- fill pass A: bin edges into 8 per-XCD queues (single read of ei) ----
__global__ __launch_bounds__(256) void fillA_kernel(
    const int* __restrict__ src, const int* __restrict__ dst,
    int* __restrict__ gcur, int2* __restrict__ epair) {
    __shared__ int lcnt[8];
    __shared__ int lbase[8];
    int tid = threadIdx.x;
    int base = blockIdx.x * CHUNK;
    if (tid < 8) lcnt[tid] = 0;
    __syncthreads();

    int sd[8], ss[8], bk[8], off[8];
    #pragma unroll
    for (int it = 0; it < 8; ++it) {
        int e = base + it * 256 + tid;
        bk[it] = -1;
        if (e < E_EDGES) {
            sd[it] = dst[e];
            ss[it] = src[e];
            bk[it] = (sd[it] >> BSHIFT) & 7;
            off[it] = atomicAdd(&lcnt[bk[it]], 1);
        }
    }
    __syncthreads();
    if (tid < 8) lbase[tid] = atomicAdd(&gcur[tid], lcnt[tid]);
    __syncthreads();
    #pragma unroll
    for (int it = 0; it < 8; ++it) {
        if (bk[it] >= 0)
            epair[lbase[bk[it]] + off[it]] = make_int2(ss[it], sd[it]);
    }
}

// ---- fill pass B2: bin XCD queue by stripe (98 buckets per XCD) ----------
__global__ __launch_bounds__(256) void fillB2_kernel(
    const int2* __restrict__ epair1, const int* __restrict__ gcur,
    int* __restrict__ scur, int2* __restrict__ epair2) {
    __shared__ int lcnt[98];
    __shared__ int lbase[98];
    int tid = threadIdx.x;
    int g = blockIdx.x & 7;
    int c = blockIdx.x >> 3;
    int ebeg = g * BCAP + c * CHUNK;
    int eend = gcur[g];
    if (tid < 98) lcnt[tid] = 0;
    __syncthreads();

    int2 pp[8]; int bk[8], off[8];
    #pragma unroll
    for (int it = 0; it < 8; ++it) {
        int i = ebeg + it * 256 + tid;
        bk[it] = -1;
        if (i < eend) {
            pp[it] = epair1[i];
            bk[it] = pp[it].y >> 10;               // fine bucket within XCD
            off[it] = atomicAdd(&lcnt[bk[it]], 1);
        }
    }
    __syncthreads();
    if (tid < 98 && lcnt[tid] > 0)
        lbase[tid] = atomicAdd(&scur[(tid << 3) | g], lcnt[tid]);
    __syncthreads();
    #pragma unroll
    for (int it = 0; it < 8; ++it) {
        if (bk[it] >= 0)
            epair2[lbase[bk[it]] + off[it]] = pp[it];
    }
}

// ---- fill pass C2: per-stripe degree-count + scan + place + seq write ----
__global__ __launch_bounds__(256) void fillC2_kernel(
    const int2* __restrict__ epair2, const int* __restrict__ scur,
    int* __restrict__ rbeg, int* __restrict__ rend, int* __restrict__ nbr) {
    __shared__ int cnt[128];
    __shared__ int loc[128];
    __shared__ int off[128];
    __shared__ int buf[SNBR];
    __shared__ int stotal;
    int s = blockIdx.x;
    int tid = threadIdx.x;
    int node0 = s << 7;
    int qbeg = s * SCAP;
    int qend = scur[s];                    // base + count after fillB2
    if (tid < 128) cnt[tid] = 0;
    __syncthreads();

    for (int i = qbeg + tid; i < qend; i += 256)
        atomicAdd(&cnt[epair2[i].y & 127], 1);
    __syncthreads();

    int v = (tid < 128) ? PAD8(cnt[tid]) : 0;
    if (tid < 128) loc[tid] = v;
    __syncthreads();
    for (int o = 1; o < 128; o <<= 1) {
        int u = (tid < 128 && tid >= o) ? loc[tid - o] : 0;
        __syncthreads();
        if (tid < 128) loc[tid] += u;
        __syncthreads();
    }
    int sbase = s * SNBR;
    if (tid < 128) {
        int ex = loc[tid] - v;             // exclusive prefix
        off[tid] = ex;
        int node = node0 + tid;
        if (node < N_NODES) {
            rbeg[node] = sbase + ex;
            rend[node] = sbase + ex + v;   // padded end
        }
    }
    if (tid == 0) stotal = loc[127];
    __syncthreads();
    int total = stotal;

    for (int i = tid; i < total; i += 256) buf[i] = N_NODES;   // sentinels
    __syncthreads();

    for (int i = qbeg + tid; i < qend; i += 256) {
        int2 p = epair2[i];
        int pos = atomicAdd(&off[p.y & 127], 1);
        buf[pos] = p.x;
    }
    __syncthreads();

    for (int i = tid * 4; i < total; i += 1024)
        *reinterpret_cast<int4*>(nbr + sbase + i) = *reinterpret_cast<const int4*>(buf + i);
}

// -------------------- x f32 -> bf16 (layer 0 only) ------------------------
__global__ __launch_bounds__(256) void tobf_kernel(const float* __restrict__ x,
                                                   uint* __restrict__ xbf) {
    int i = blockIdx.x * 256 + threadIdx.x;   // N*8 threads, 8 floats each
    if (i < N_NODES * 8) {
        float4 a = reinterpret_cast<const float4*>(x)[i * 2];
        float4 b = reinterpret_cast<const float4*>(x)[i * 2 + 1];
        uint4 o;
        o.x = bf_pack(a.x, a.y);
        o.y = bf_pack(a.z, a.w);
        o.z = bf_pack(b.x, b.y);
        o.w = bf_pack(b.z, b.w);
        reinterpret_cast<uint4*>(xbf)[i] = o;
    }
    if (i < 8) reinterpret_cast<uint4*>(xbf)[N_NODES * 8 + i] = make_uint4(0, 0, 0, 0);
}

// ------- fused gather(bf16, padded CSR, idx-prefetch) + MFMA GEMM1 --------
__global__ __launch_bounds__(256) void gemm1_fused_kernel(
    const uint* __restrict__ xbf, const int* __restrict__ rbeg,
    const int* __restrict__ rend, const int* __restrict__ nbr,
    const float* __restrict__ W1, const float* __restrict__ b1,
    unsigned short* __restrict__ h16, float* __restrict__ stats) {
    __shared__ unsigned short sA[64][72];        // bf16 agg tile (pad: 2-way alias)
    __shared__ unsigned short sW[64][72];        // bf16 W^T [col][k]
    int tid = threadIdx.x;
    int row0 = blockIdx.x * 64;

    // stage W1 transposed to [col][k]
    for (int i = tid; i < 1024; i += 256) {
        int k = i >> 4, cb = (i & 15) * 4;
        float4 w = reinterpret_cast<const float4*>(W1)[i];
        sW[cb + 0][k] = bf1(w.x);
        sW[cb + 1][k] = bf1(w.y);
        sW[cb + 2][k] = bf1(w.z);
        sW[cb + 3][k] = bf1(w.w);
    }

    const uint4* xb4 = reinterpret_cast<const uint4*>(xbf);
    int c8 = tid & 7;        // uint4 slot within row (8 bf16 cols)
    int rslot = tid >> 3;    // 32 rows per pass
    for (int rr = 0; rr < 2; ++rr) {
        int r = rslot + 32 * rr;
        int gr = row0 + r;
        float a0 = 0.f, a1 = 0.f, a2 = 0.f, a3 = 0.f;
        float a4 = 0.f, a5 = 0.f, a6 = 0.f, a7 = 0.f;
        if (gr < N_NODES) {
            uint4 sv = xb4[(size_t)gr * 8 + c8];
            a0 = lo16(sv.x); a1 = hi16(sv.x); a2 = lo16(sv.y); a3 = hi16(sv.y);
            a4 = lo16(sv.z); a5 = hi16(sv.z); a6 = lo16(sv.w); a7 = hi16(sv.w);
            int beg = rbeg[gr], end = rend[gr];
            int4 ia = *reinterpret_cast<const int4*>(nbr + beg);
            int4 ib = *reinterpret_cast<const int4*>(nbr + beg + 4);
            for (int j = beg; j < end; j += 8) {
                int4 ian = *reinterpret_cast<const int4*>(nbr + j + 8);
                int4 ibn = *reinterpret_cast<const int4*>(nbr + j + 12);
                uint4 v0 = xb4[(size_t)ia.x * 8 + c8];
                uint4 v1 = xb4[(size_t)ia.y * 8 + c8];
                uint4 v2 = xb4[(size_t)ia.z * 8 + c8];
                uint4 v3 = xb4[(size_t)ia.w * 8 + c8];
                uint4 v4 = xb4[(size_t)ib.x * 8 + c8];
                uint4 v5 = xb4[(size_t)ib.y * 8 + c8];
                uint4 v6 = xb4[(size_t)ib.z * 8 + c8];
                uint4 v7 = xb4[(size_t)ib.w * 8 + c8];
                a0 += lo16(v0.x); a1 += hi16(v0.x); a2 += lo16(v0.y); a3 += hi16(v0.y);
                a4 += lo16(v0.z); a5 += hi16(v0.z); a6 += lo16(v0.w); a7 += hi16(v0.w);
                a0 += lo16(v1.x); a1 += hi16(v1.x); a2 += lo16(v1.y); a3 += hi16(v1.y);
                a4 += lo16(v1.z); a5 += hi16(v1.z); a6 += lo16(v1.w); a7 += hi16(v1.w);
                a0 += lo16(v2.x); a1 += hi16(v2.x); a2 += lo16(v2.y); a3 += hi16(v2.y);
                a4 += lo16(v2.z); a5 += hi16(v2.z); a6 += lo16(v2.w); a7 += hi16(v2.w);
                a0 += lo16(v3.x); a1 += hi16(v3.x); a2 += lo16(v3.y); a3 += hi16(v3.y);
                a4 += lo16(v3.z); a5 += hi16(v3.z); a6 += lo16(v3.w); a7 += hi16(v3.w);
                a0 += lo16(v4.x); a1 += hi16(v4.x); a2 += lo16(v4.y); a3 += hi16(v4.y);
                a4 += lo16(v4.z); a5 += hi16(v4.z); a6 += lo16(v4.w); a7 += hi16(v4.w);
                a0 += lo16(v5.x); a1 += hi16(v5.x); a2 += lo16(v5.y); a3 += hi16(v5.y);
                a4 += lo16(v5.z); a5 += hi16(v5.z); a6 += lo16(v5.w); a7 += hi16(v5.w);
                a0 += lo16(v6.x); a1 += hi16(v6.x); a2 += lo16(v6.y); a3 += hi16(v6.y);
                a4 += lo16(v6.z); a5 += hi16(v6.z); a6 += lo16(v6.w); a7 += hi16(v6.w);
                a0 += lo16(v7.x); a1 += hi16(v7.x); a2 += lo16(v7.y); a3 += hi16(v7.y);
                a4 += lo16(v7.z); a5 += hi16(v7.z); a6 += lo16(v7.w); a7 += hi16(v7.w);
                ia = ian; ib = ibn;
            }
        }
        uint4 o;
        o.x = bf_pack(a0, a1); o.y = bf_pack(a2, a3);
        o.z = bf_pack(a4, a5); o.w = bf_pack(a6, a7);
        *reinterpret_cast<uint4*>(&sA[r][c8 * 8]) = o;
    }
    __syncthreads();

    // MFMA GEMM: wave w owns rows [16w,16w+16); 4 col-tiles x 2 K-chunks
    int w = tid >> 6;
    int l = tid & 63;
    int lr = l & 15;         // A-row within tile / D-col
    int lk = l >> 4;         // k-group / D row-group
    f32x4 acc[4];
    #pragma unroll
    for (int ct = 0; ct < 4; ++ct) {
        float b = b1[ct * 16 + lr];
        acc[ct] = (f32x4){b, b, b, b};
    }
    #pragma unroll
    for (int ct = 0; ct < 4; ++ct) {
        #pragma unroll
        for (int kc = 0; kc < 2; ++kc) {
            bf16x8 av = *reinterpret_cast<const bf16x8*>(&sA[w * 16 + lr][kc * 32 + lk * 8]);
            bf16x8 bv = *reinterpret_cast<const bf16x8*>(&sW[ct * 16 + lr][kc * 32 + lk * 8]);
            acc[ct] = __builtin_amdgcn_mfma_f32_16x16x32_bf16(av, bv, acc[ct], 0, 0, 0);
        }
    }

    // epilogue: h16 write + BN stats from accumulators
    float s4[4] = {0.f, 0.f, 0.f, 0.f};   // per-ct col partial sums
    float q4[4] = {0.f, 0.f, 0.f, 0.f};
    #pragma unroll
    for (int ct = 0; ct < 4; ++ct) {
        #pragma unroll
        for (int r = 0; r < 4; ++r) {
            int row = row0 + w * 16 + lk * 4 + r;
            float v = acc[ct][r];
            if (row < N_NODES) {
                h16[(size_t)row * 64 + ct * 16 + lr] = bf1(v);
                s4[ct] += v;
                q4[ct] += v * v;
            }
        }
    }
    __syncthreads();                       // all MFMA reads of sW done
    float* scr = reinterpret_cast<float*>(&sW[0][0]);   // 2048 f32 <= 2304 avail
    int g16 = w * 4 + lk;                  // 0..15
    #pragma unroll
    for (int ct = 0; ct < 4; ++ct) {
        scr[g16 * 64 + ct * 16 + lr] = s4[ct];
        scr[1024 + g16 * 64 + ct * 16 + lr] = q4[ct];
    }
    __syncthreads();
    if (tid < 64) {
        float s = 0.f, q = 0.f;
        #pragma unroll
        for (int r2 = 0; r2 < 16; ++r2) {
            s += scr[r2 * 64 + tid];
            q += scr[1024 + r2 * 64 + tid];
        }
        unsafeAtomicAdd(&stats[tid], s);
        unsafeAtomicAdd(&stats[64 + tid], q);
    }
}

// -- MFMA GEMM2 + pool (64 rows/block); xout write skipped when null -------
__global__ __launch_bounds__(256) void gemm2_pool_kernel(
    const unsigned short* __restrict__ h16, const float* __restrict__ stats,
    const float* __restrict__ gamma, const float* __restrict__ beta,
    const float* __restrict__ W2, const float* __restrict__ b2,
    const int* __restrict__ batch, float* __restrict__ pooled,
    unsigned short* __restrict__ xout) {
    __shared__ unsigned short sA[64][72];
    __shared__ unsigned short sW[64][72];
    int tid = threadIdx.x;
    int row0 = blockIdx.x * 64;

    // stage W2 transposed to [col][k]
    for (int i = tid; i < 1024; i += 256) {
        int k = i >> 4, cb = (i & 15) * 4;
        float4 w = reinterpret_cast<const float4*>(W2)[i];
        sW[cb + 0][k] = bf1(w.x);
        sW[cb + 1][k] = bf1(w.y);
        sW[cb + 2][k] = bf1(w.z);
        sW[cb + 3][k] = bf1(w.w);
    }

    // per-thread BN scale/shift for its fixed 8 staging columns
    int c8 = tid & 7;
    float scv[8], shv[8];
    #pragma unroll
    for (int k = 0; k < 8; ++k) {
        int col = c8 * 8 + k;
        float mu = stats[col] * (1.0f / N_NODES);
        float var = stats[64 + col] * (1.0f / N_NODES) - mu * mu;
        scv[k] = gamma[col] * rsqrtf(var + BN_EPS);
        shv[k] = beta[col] - mu * scv[k];
    }

    const uint4* h4 = reinterpret_cast<const uint4*>(h16);
    for (int i = tid; i < 512; i += 256) {
        int r = i >> 3;                    // (i&7) == c8 since 256 % 8 == 0
        int gr = row0 + r;
        float o[8] = {0.f, 0.f, 0.f, 0.f, 0.f, 0.f, 0.f, 0.f};
        if (gr < N_NODES) {
            uint4 v = h4[(size_t)gr * 8 + c8];
            float f[8] = {lo16(v.x), hi16(v.x), lo16(v.y), hi16(v.y),
                          lo16(v.z), hi16(v.z), lo16(v.w), hi16(v.w)};
            #pragma unroll
            for (int k = 0; k < 8; ++k)
                o[k] = fmaxf(fmaf(f[k], scv[k], shv[k]), 0.f);
        }
        uint4 p;
        p.x = bf_pack(o[0], o[1]); p.y = bf_pack(o[2], o[3]);
        p.z = bf_pack(o[4], o[5]); p.w = bf_pack(o[6], o[7]);
        *reinterpret_cast<uint4*>(&sA[r][c8 * 8]) = p;
    }
    __syncthreads();

    int w = tid >> 6;
    int l = tid & 63;
    int lr = l & 15;
    int lk = l >> 4;
    f32x4 acc[4];
    #pragma unroll
    for (int ct = 0; ct < 4; ++ct) {
        float b = b2[ct * 16 + lr];
        acc[ct] = (f32x4){b, b, b, b};
    }
    #pragma unroll
    for (int ct = 0; ct < 4; ++ct) {
        #pragma unroll
        for (int kc = 0; kc < 2; ++kc) {
            bf16x8 av = *reinterpret_cast<const bf16x8*>(&sA[w * 16 + lr][kc * 32 + lk * 8]);
            bf16x8 bv = *reinterpret_cast<const bf16x8*>(&sW[ct * 16 + lr][kc * 32 + lk * 8]);
            acc[ct] = __builtin_amdgcn_mfma_f32_16x16x32_bf16(av, bv, acc[ct], 0, 0, 0);
        }
    }

    // write xout (bf16) unless last layer
    if (xout) {
        #pragma unroll
        for (int ct = 0; ct < 4; ++ct) {
            #pragma unroll
            for (int r = 0; r < 4; ++r) {
                int row = row0 + w * 16 + lk * 4 + r;
                if (row < N_NODES)
                    xout[(size_t)row * 64 + ct * 16 + lr] = bf1(acc[ct][r]);
            }
        }
    }

    // pool: single-graph block -> LDS reduce + 1 atomic/col; else run-length
    int lastrow = row0 + 63; if (lastrow >= N_NODES) lastrow = N_NODES - 1;
    int b0 = batch[row0 < N_NODES ? row0 : N_NODES - 1], bL = batch[lastrow];
    int g16 = w * 4 + lk;
    if (b0 == bL) {
        float ps[4] = {0.f, 0.f, 0.f, 0.f};
        #pragma unroll
        for (int ct = 0; ct < 4; ++ct) {
            #pragma unroll
            for (int r = 0; r < 4; ++r) {
                int row = row0 + w * 16 + lk * 4 + r;
                if (row < N_NODES) ps[ct] += acc[ct][r];
            }
        }
        __syncthreads();                   // MFMA reads of sW done
        float* scr = reinterpret_cast<float*>(&sW[0][0]);
        #pragma unroll
        for (int ct = 0; ct < 4; ++ct)
            scr[g16 * 64 + ct * 16 + lr] = ps[ct];
        __syncthreads();
        if (tid < 64) {
            float s = 0.f;
            #pragma unroll
            for (int r2 = 0; r2 < 16; ++r2) s += scr[r2 * 64 + tid];
            unsafeAtomicAdd(&pooled[b0 * 64 + tid], s);
        }
    } else {
        #pragma unroll
        for (int ct = 0; ct < 4; ++ct) {
            float pacc = 0.f;
            int curb = -1;
            int col = ct * 16 + lr;
            #pragma unroll
            for (int r = 0; r < 4; ++r) {
                int row = row0 + w * 16 + lk * 4 + r;
                if (row < N_NODES) {
                    int b = batch[row];
                    if (b != curb) {
                        if (curb >= 0) unsafeAtomicAdd(&pooled[curb * 64 + col], pacc);
                        curb = b;
                        pacc = 0.f;
                    }
                    pacc += acc[ct][r];
                }
            }
            if (curb >= 0) unsafeAtomicAdd(&pooled[curb * 64 + col], pacc);
        }
    }
}

// ------- output (all layers): score = sum_l pooled_l @ Wout_l + bout_l ----
__global__ void out3_kernel(const float* __restrict__ pooled3,
                            const float* __restrict__ Wout,
                            const float* __restrict__ bout,
                            float* __restrict__ score) {
    int idx = blockIdx.x * blockDim.x + threadIdx.x;
    if (idx >= G_GRAPHS * OUT_F) return;
    int g = idx / OUT_F;
    int o = idx - g * OUT_F;
    float acc = 0.f;
    for (int l = 0; l < L_LAYERS; ++l) {
        acc += bout[l * OUT_F + o];
        const float* pl = pooled3 + (size_t)l * G_GRAPHS * 64 + g * 64;
        const float* wl = Wout + l * 64 * OUT_F;
        #pragma unroll
        for (int k = 0; k < 64; ++k) acc += pl[k] * wl[k * OUT_F + o];
    }
    score[idx] = acc;
}

extern "C" void kernel_launch(void* const* d_in, const int* in_sizes, int n_in,
                              void* d_out, int out_size, void* d_ws, size_t ws_size,
                              hipStream_t stream) {
    const float* x     = (const float*)d_in[0];
    const int*   ei    = (const int*)d_in[1];
    const int*   batch = (const int*)d_in[2];
    const float* W1    = (const float*)d_in[3];
    const float* b1    = (const float*)d_in[4];
    const float* gamma = (const float*)d_in[5];
    const float* beta  = (const float*)d_in[6];
    const float* W2    = (const float*)d_in[7];
    const float* b2    = (const float*)d_in[8];
    const float* Wout  = (const float*)d_in[9];
    const float* bout  = (const float*)d_in[10];
    float* out = (float*)d_out;

    unsigned short* H16 = (unsigned short*)d_ws;             // N*64 bf16
    uint*  XBF    = (uint*)(H16 + (size_t)N_NODES * 64);     // (N+1)*32 uints
    float* stats3 = (float*)(XBF + (size_t)(N_NODES + 1) * 32);  // 3*128
    float* pooled3= stats3 + 3 * 128;                        // 3*G*64
    int*   gcur   = (int*)(pooled3 + (size_t)3 * G_GRAPHS * 64); // 8
    int*   scur   = gcur + 8;                                // 784 (pad)
    int*   rbeg   = scur + 784;                              // N
    int*   rend   = rbeg + N_NODES;                          // N
    int*   nbr    = rend + N_NODES;                          // NSTRIPE*SNBR + 16
    int2*  epair1 = (int2*)(nbr + (size_t)NSTRIPE * SNBR + 16);  // 8*BCAP pairs
    int2*  epair2 = epair1 + (size_t)8 * BCAP;               // NSTRIPE*SCAP pairs

    const int* src = ei;
    const int* dst = ei + E_EDGES;

    // zero all per-layer stats+pooled in one shot
    (void)hipMemsetAsync(stats3, 0, (3 * 128 + (size_t)3 * G_GRAPHS * 64) * sizeof(float), stream);

    init_kernel<<<(NSTRIPE + 255) / 256, 256, 0, stream>>>(gcur, scur);
    fillA_kernel<<<NCHUNK, 256, 0, stream>>>(src, dst, gcur, epair1);
    fillB2_kernel<<<FB_GRID, 256, 0, stream>>>(epair1, gcur, scur, epair2);
    fillC2_kernel<<<NSTRIPE, 256, 0, stream>>>(epair2, scur, rbeg, rend, nbr);
    tobf_kernel<<<(N_NODES * 8 + 255) / 256, 256, 0, stream>>>(x, XBF);

    int nb = (N_NODES + 63) / 64;

    for (int l = 0; l < L_LAYERS; ++l) {
        float* stats = stats3 + l * 128;
        float* pooled = pooled3 + (size_t)l * G_GRAPHS * 64;
        gemm1_fused_kernel<<<nb, 256, 0, stream>>>(XBF, rbeg, rend, nbr,
            W1 + l * 64 * 64, b1 + l * 64, H16, stats);
        unsigned short* xout = (l == L_LAYERS - 1) ? (unsigned short*)nullptr
                                                   : (unsigned short*)XBF;
        gemm2_pool_kernel<<<nb, 256, 0, stream>>>(H16, stats,
            gamma + l * 64, beta + l * 64, W2 + l * 64 * 64, b2 + l * 64, batch,
            pooled, xout);
    }
    out3_kernel<<<(G_GRAPHS * OUT_F + 127) / 128, 128, 0, stream>>>(
        pooled3, Wout, bout, out);
}